// Round 2
// baseline (188.922 us; speedup 1.0000x reference)
//
#include <hip/hip_runtime.h>
#include <hip/hip_bf16.h>

// 2D-MDLSTM (4 directions) + FC head for MI355X — round 17.
//
// R16 post-mortem: absolute-row mapping REGRESSED (83->101 us). Critical
// wave-task count went 78->82 (boundary steps pay a full task for 1 active
// row), and global-x + C-init FMAs put L1 latency + extra VALU work on the
// barrier-locked serial path (MfmaUtil 25->18.7, VALUBusy 53->48: both
// pipes idler while time grew = added bubbles). mdlstm reverted to R12
// verbatim (measured 82.9 us, critical-count floor of the 256-WG layout).
//
// R17 lever: the 69 us OUTSIDE mdlstm. R14 showed one kernel boundary in
// this harness ~= 23 us. Fuse the FC head as a per-tile producer-consumer
// tail (no grid sync, no MFMA-chain split — R14's mistakes): the 4 WGs
// (d=0..3) of one batch-pair tile are all co-resident (256 WGs on 256 CUs);
// d<3 WGs release a per-(tile,d) flag after their Hout stores, the d==3 WG
// acquires all 3 and runs FC for its 2 batches with 2x256 threads.
// 64 consumer WGs x dual-256-FC = same parallelism as the old 128-WG fc
// kernel, zero extra launch. Safety: flags cleared in the prologue (~80 us
// before any consumer spins), device-scope acq/rel atomics (G16, cross-XCD),
// magic values so stale/poisoned ws can never satisfy the spin before the
// clear lands, and a ws_size check falling back to the two-kernel path.

#define GRIDN 28
#define BATCH 128
#define HID   64
#define NDIR  4
#define FC_HD 512
#define OUT_N 10
#define BT    2
#define NTHR  512
#define NSLOT 29          // 28 frontier rows + permanent-zero row (r = -1)
#define S_H   104         // f16/slot: [0,64) h | [64]=x [65]=1 [66,96)=0 | 8 pad
#define S_C   68          // float/slot: 64 c + 4 pad

typedef _Float16 f16;
typedef _Float16 f16x8 __attribute__((ext_vector_type(8)));
typedef float    f32x4 __attribute__((ext_vector_type(4)));

#define LOG2E  1.44269504088896340736f
#define LOG2E2 2.88539008177792681472f

__device__ __forceinline__ float rcpf(float x) { return __builtin_amdgcn_rcpf(x); }
__device__ __forceinline__ float ex2(float x)  { return __builtin_amdgcn_exp2f(x); }

__global__ __launch_bounds__(NTHR)
void mdlstm_kernel(const float* __restrict__ x,    // [B][28][28]
                   const float* __restrict__ Wx,   // [4][320]
                   const float* __restrict__ U,    // [4][128][320]
                   const float* __restrict__ bias, // [4][320]
                   float* __restrict__ Hout,       // [4][B][64] (workspace)
                   const float* __restrict__ W1,   // [256][512]
                   const float* __restrict__ fb1,  // [512]
                   const float* __restrict__ W2,   // [512][10]
                   const float* __restrict__ fb2,  // [10]
                   float* __restrict__ out,        // [B][10]
                   unsigned* __restrict__ flags)   // [64][4] in ws, or nullptr
{
    const int d    = blockIdx.x & 3;
    const int tile = blockIdx.x >> 2;     // 0..63 batch-pair
    const int tid  = threadIdx.x;
    const int lane = tid & 63;
    const int wave = tid >> 6;            // 0..7
    const int wm   = wave >> 2;           // tile parity 0/1
    const int wh   = wave & 3;            // h-subtile (n = wh*16 + l16)
    const int l16  = lane & 15;
    const int q    = lane >> 4;
    const int nb   = wh * 16 + l16;       // this lane's h index 0..63

    __shared__ __align__(16) f16 Fh[2][BT][NSLOT * S_H];
    __shared__ float             Fc[2][BT][NSLOT * S_C];
    __shared__ float             xs[GRIDN][GRIDN][BT];
    // FC-tail scratch (dead during the recurrence; 1 WG/CU so the extra
    // 8.3 KiB LDS cannot change occupancy)
    __shared__ float hrow2[BT][NDIR * HID];
    __shared__ float z1s[BT][FC_HD];
    __shared__ float ps2[BT][16][16];
    __shared__ float z2s[BT][16];

    // clear handoff flags FIRST (consumers can only spin ~80 us from now,
    // after their own 55-step recurrence — stale/poisoned values are long
    // cleared by then)
    if (flags && d < 3 && tid == 0)
        __hip_atomic_store(&flags[tile * 4 + d], 0u,
                           __ATOMIC_RELAXED, __HIP_MEMORY_SCOPE_AGENT);

    for (int i = tid; i < 2 * BT * NSLOT * S_H; i += NTHR) ((f16*)Fh)[i] = (f16)0.0f;
    for (int i = tid; i < 2 * BT * NSLOT * S_C; i += NTHR) ((float*)Fc)[i] = 0.0f;
    for (int i = tid; i < GRIDN * GRIDN * BT; i += NTHR) {
        int bl = i & 1, rc = i >> 1, c = rc % GRIDN, r = rc / GRIDN;
        int rr = (d & 2) ? (GRIDN - 1 - r) : r;
        int cc = (d & 1) ? (GRIDN - 1 - c) : c;
        xs[r][c][bl] = x[((tile * BT + bl) * GRIDN + rr) * GRIDN + cc];
    }

    // ---- B-fragments in registers, gate-scaled: 25 x f16x8 (100 regs)
    // sigmoid gates scaled by -log2e (sig = rcp(1+2^acc)); g gate by +2log2e.
    f16x8 bf[5][5];
#pragma unroll
    for (int g = 0; g < 5; ++g) {
        const float sc = (g == 4) ? LOG2E2 : -LOG2E;
        int n = g * 64 + nb;
#pragma unroll
        for (int ks = 0; ks < 4; ++ks) {
            f16x8 v;
            int kb = ks * 32 + q * 8;
#pragma unroll
            for (int j = 0; j < 8; ++j)
                v[j] = (f16)(sc * U[(d * 128 + kb + j) * 320 + n]);
            bf[g][ks] = v;
        }
        f16x8 v5 = {(f16)0, (f16)0, (f16)0, (f16)0, (f16)0, (f16)0, (f16)0, (f16)0};
        if (q == 0) {
            v5[0] = (f16)(sc * Wx[d * 320 + n]);
            v5[1] = (f16)(sc * bias[d * 320 + n]);
        }
        bf[g][4] = v5;
    }
    __syncthreads();   // zero-init complete

    // ones in the x-region ([65]=1) of every slot, both buffers; seed x(0,0)
    if (tid < 2 * BT * NSLOT) {
        int buf = tid / (BT * NSLOT), rem = tid % (BT * NSLOT);
        int b = rem / NSLOT, sl = rem % NSLOT;
        Fh[buf][b][sl * S_H + 65] = (f16)1.0f;
    }
    if (tid < BT) Fh[0][tid][27 * S_H + 64] = (f16)xs[0][0][tid];
    __syncthreads();

    // one anti-diagonal; br is a literal at every callsite -> const-folds
    auto step = [&](int t, int br) __attribute__((always_inline)) {
        const int bw  = br ^ 1;
        const int rlo = (t > GRIDN - 1) ? (t - (GRIDN - 1)) : 0;
        const int rhi = (t < GRIDN - 1) ? t : (GRIDN - 1);
        const int k   = rhi - rlo + 1;
        const int nM  = (2 * k + 15) >> 4;

        // stage x for diagonal t+1 into the write buffer (tail lanes of last wave)
        if (t < 2 * GRIDN - 2 && tid >= NTHR - 56) {
            int idx = tid - (NTHR - 56), b = idx & 1, j = idx >> 1;
            int rlo2 = (t + 1 > GRIDN - 1) ? (t + 1 - (GRIDN - 1)) : 0;
            int rhi2 = (t + 1 < GRIDN - 1) ? (t + 1) : (GRIDN - 1);
            if (j <= rhi2 - rlo2) {
                int r = rlo2 + j;
                Fh[bw][b][(27 - r) * S_H + 64] = (f16)xs[r][t + 1 - r][b];
            }
        }

        for (int mt = wm; mt < nM; mt += 2) {
            // ---- A fragments: task row mA -> (batch bA, grid row rA)
            int mA = mt * 16 + l16;
            int jA = mA >> 1; if (jA > k - 1) jA = k - 1;
            int bA = mA & 1;
            int slA = 27 - (rlo + jA);
            const f16* ab = &Fh[br][bA][slA * S_H];
            f16x8 a0 = *(const f16x8*)(ab + q * 8);              // h_left k 0..63
            f16x8 a1 = *(const f16x8*)(ab + 32 + q * 8);
            f16x8 a2 = *(const f16x8*)(ab + S_H + q * 8);        // h_up   k 64..127
            f16x8 a3 = *(const f16x8*)(ab + S_H + 32 + q * 8);
            f16x8 a4 = *(const f16x8*)(ab + 64 + q * 8);         // {x,1,0..} k 128..159

            // ---- epilogue addresses + c-state PRELOAD (before MFMAs: their
            // ~120 cyc LDS latency drains under the MFMA block)
            int j0  = mt * 8 + q * 2;
            int jj0 = (j0     > k - 1) ? k - 1 : j0;
            int jj1 = (j0 + 1 > k - 1) ? k - 1 : j0 + 1;
            int sl0 = 27 - (rlo + jj0);
            int sl1 = 27 - (rlo + jj1);
            const float* rp[4] = { &Fc[br][0][sl0 * S_C + nb], &Fc[br][1][sl0 * S_C + nb],
                                   &Fc[br][0][sl1 * S_C + nb], &Fc[br][1][sl1 * S_C + nb] };
            float pcl[4], pcu[4];
#pragma unroll
            for (int i = 0; i < 4; ++i) { pcl[i] = rp[i][0]; pcu[i] = rp[i][S_C]; }

            const f32x4 z4 = {0.f, 0.f, 0.f, 0.f};               // shared zero-C
            f32x4 acc[5];
#pragma unroll
            for (int g = 0; g < 5; ++g) acc[g] = __builtin_amdgcn_mfma_f32_16x16x32_f16(a4, bf[g][4], z4, 0, 0, 0);
#pragma unroll
            for (int g = 0; g < 5; ++g) acc[g] = __builtin_amdgcn_mfma_f32_16x16x32_f16(a0, bf[g][0], acc[g], 0, 0, 0);
#pragma unroll
            for (int g = 0; g < 5; ++g) acc[g] = __builtin_amdgcn_mfma_f32_16x16x32_f16(a1, bf[g][1], acc[g], 0, 0, 0);
#pragma unroll
            for (int g = 0; g < 5; ++g) acc[g] = __builtin_amdgcn_mfma_f32_16x16x32_f16(a2, bf[g][2], acc[g], 0, 0, 0);
#pragma unroll
            for (int g = 0; g < 5; ++g) acc[g] = __builtin_amdgcn_mfma_f32_16x16x32_f16(a3, bf[g][3], acc[g], 0, 0, 0);

            // ---- gates + state, BRANCHLESS, trans-merged.
            // acc0=-log2e*i  acc1=-log2e*f1  acc2=-log2e*f2  acc3=-log2e*o
            // acc4=+2log2e*g
            //   sig(i)*tanh(g)        = (tb-2)*rcp(ta*tb)
            //   sig(f1)*cl+sig(f2)*cu = (cl*tq+cu*tp)*rcp(tp*tq)
            //   sig(o)*tanh(cn)       = (te-2)*rcp(td*te), cn clamped to 22
            //     for te only (tanh(22)==1.0f exactly; prevents te=inf ->
            //     inf*0=NaN when the accumulated c exceeds 44 — the R11 bug).
            const int DC = (bw - br) * (BT * NSLOT * S_C);   // compile-time
            int ih0 = sl0 * S_H + nb, ih1 = sl1 * S_H + nb;
            f16* wh0 = &Fh[bw][0][0];
            f16* wh1 = &Fh[bw][1][0];
#pragma unroll
            for (int i = 0; i < 4; ++i) {
                float ta = 1.0f + ex2(acc[0][i]);
                float tp = 1.0f + ex2(acc[1][i]);
                float tq = 1.0f + ex2(acc[2][i]);
                float td = 1.0f + ex2(acc[3][i]);
                float tb = 1.0f + ex2(acc[4][i]);
                float cn = (tb - 2.0f) * rcpf(ta * tb)
                         + (pcl[i] * tq + pcu[i] * tp) * rcpf(tp * tq);
                float cnc = fminf(cn, 22.0f);
                float te = 1.0f + ex2(LOG2E2 * cnc);
                float hn = (te - 2.0f) * rcpf(td * te);
                *(float*)(rp[i] + DC) = cn;
                ((i & 1) ? wh1 : wh0)[(i < 2) ? ih0 : ih1] = (f16)hn;
            }
        }
        __syncthreads();
    };

    for (int tb = 0; tb < 27; ++tb) { step(2 * tb, 0); step(2 * tb + 1, 1); }
    step(54, 0);

    // final h(27,27): t=54 wrote buf 1, slot 0
    if (tid < BT * HID) {
        int bl = tid >> 6, h = tid & 63;
        Hout[(d * BATCH + tile * BT + bl) * HID + h] = (float)Fh[1][bl][h];
    }

    // ================= fused FC head (per-tile handoff) =================
    if (!flags) return;
    __syncthreads();   // all Hout stores of this WG drained (vmcnt0+barrier)

    if (d < 3) {
        // producer: release flag, done
        if (tid == 0) {
            __threadfence();
            __hip_atomic_store(&flags[tile * 4 + d],
                               0x5EEDBE00u | (unsigned)(tile * 4 + d),
                               __ATOMIC_RELEASE, __HIP_MEMORY_SCOPE_AGENT);
        }
        return;
    }

    // consumer (d == 3): acquire the 3 peer flags, then FC for 2 batches
    if (tid < 3) {
        unsigned want = 0x5EEDBE00u | (unsigned)(tile * 4 + tid);
        while (__hip_atomic_load(&flags[tile * 4 + tid],
                                 __ATOMIC_ACQUIRE, __HIP_MEMORY_SCOPE_AGENT) != want)
            __builtin_amdgcn_s_sleep(2);
    }
    __syncthreads();
    __threadfence();

    const int g = tid >> 8;          // batch sub-group 0/1
    const int t = tid & 255;
    const int b = tile * BT + g;

    hrow2[g][t] = Hout[(t >> 6) * (BATCH * HID) + b * HID + (t & 63)];
    __syncthreads();

    // z1 = relu(hrow @ W1 + b1): each thread cols {t, t+256}
    {
        float s0 = fb1[t], s1 = fb1[t + 256];
#pragma unroll 8
        for (int f = 0; f < NDIR * HID; ++f) {
            float h = hrow2[g][f];
            s0 += h * W1[f * FC_HD + t];
            s1 += h * W1[f * FC_HD + t + 256];
        }
        z1s[g][t]       = fmaxf(s0, 0.0f);
        z1s[g][t + 256] = fmaxf(s1, 0.0f);
    }
    __syncthreads();

    // z2 partials: j = t&15 (10 used), slice = t>>4 covers 32 k each
    {
        int j = t & 15, sl = t >> 4;
        float s = 0.0f;
        if (j < OUT_N) {
#pragma unroll
            for (int i = 0; i < 32; ++i) {
                int kk = sl * 32 + i;
                s += z1s[g][kk] * W2[kk * OUT_N + j];
            }
        }
        ps2[g][sl][j] = s;
    }
    __syncthreads();

    if (t < OUT_N) {
        float s = fb2[t];
#pragma unroll
        for (int sl = 0; sl < 16; ++sl) s += ps2[g][sl][t];
        z2s[g][t] = s;
    }
    __syncthreads();

    if (t == 0) {
        float m = z2s[g][0];
        for (int j = 1; j < OUT_N; ++j) m = fmaxf(m, z2s[g][j]);
        float sum = 0.0f, e[OUT_N];
        for (int j = 0; j < OUT_N; ++j) { e[j] = __expf(z2s[g][j] - m); sum += e[j]; }
        float inv = 1.0f / sum;
        for (int j = 0; j < OUT_N; ++j) out[b * OUT_N + j] = e[j] * inv;
    }
}

// Fallback FC head (used only if ws is too small for the handoff flags).
__global__ __launch_bounds__(256)
void fc_kernel(const float* __restrict__ Hin,  // [4][B][64]
               const float* __restrict__ W1, const float* __restrict__ b1,
               const float* __restrict__ W2, const float* __restrict__ b2,
               float* __restrict__ out)        // [B][10]
{
    const int b   = blockIdx.x;
    const int tid = threadIdx.x;
    __shared__ float hrow[NDIR * HID];
    __shared__ float z1[FC_HD];
    __shared__ float ps[16][16];
    __shared__ float z2[16];

    hrow[tid] = Hin[(tid >> 6) * (BATCH * HID) + b * HID + (tid & 63)];
    __syncthreads();

    {
        float s0 = b1[tid], s1 = b1[tid + 256];
#pragma unroll 8
        for (int f = 0; f < NDIR * HID; ++f) {
            float h = hrow[f];
            s0 += h * W1[f * FC_HD + tid];
            s1 += h * W1[f * FC_HD + tid + 256];
        }
        z1[tid]       = fmaxf(s0, 0.0f);
        z1[tid + 256] = fmaxf(s1, 0.0f);
    }
    __syncthreads();

    {
        int j = tid & 15, sl = tid >> 4;
        float s = 0.0f;
        if (j < OUT_N) {
#pragma unroll
            for (int i = 0; i < 32; ++i) {
                int kk = sl * 32 + i;
                s += z1[kk] * W2[kk * OUT_N + j];
            }
        }
        ps[sl][j] = s;
    }
    __syncthreads();

    if (tid < OUT_N) {
        float s = b2[tid];
#pragma unroll
        for (int sl = 0; sl < 16; ++sl) s += ps[sl][tid];
        z2[tid] = s;
    }
    __syncthreads();

    if (tid == 0) {
        float m = z2[0];
        for (int j = 1; j < OUT_N; ++j) m = fmaxf(m, z2[j]);
        float sum = 0.0f, e[OUT_N];
        for (int j = 0; j < OUT_N; ++j) { e[j] = __expf(z2[j] - m); sum += e[j]; }
        float inv = 1.0f / sum;
        for (int j = 0; j < OUT_N; ++j) out[b * OUT_N + j] = e[j] * inv;
    }
}

extern "C" void kernel_launch(void* const* d_in, const int* in_sizes, int n_in,
                              void* d_out, int out_size, void* d_ws, size_t ws_size,
                              hipStream_t stream) {
    const float* x  = (const float*)d_in[0];
    const float* Wx = (const float*)d_in[1];
    const float* U  = (const float*)d_in[2];
    const float* bs = (const float*)d_in[3];
    const float* W1 = (const float*)d_in[4];
    const float* b1 = (const float*)d_in[5];
    const float* W2 = (const float*)d_in[6];
    const float* b2 = (const float*)d_in[7];
    float* out = (float*)d_out;
    float* Hws = (float*)d_ws;   // [4][128][64] fp32 = 128 KiB

    const size_t hbytes = (size_t)NDIR * BATCH * HID * sizeof(float);
    bool fused = ws_size >= hbytes + 256 * sizeof(unsigned);
    unsigned* flags = fused ? (unsigned*)((char*)d_ws + hbytes) : nullptr;

    mdlstm_kernel<<<NDIR * (BATCH / BT), NTHR, 0, stream>>>(
        x, Wx, U, bs, Hws, W1, b1, W2, b2, out, flags);
    if (!fused)
        fc_kernel<<<BATCH, 256, 0, stream>>>(Hws, W1, b1, W2, b2, out);
}

// Round 3
// 146.116 us; speedup vs baseline: 1.2930x; 1.2930x over previous
//
#include <hip/hip_runtime.h>
#include <hip/hip_bf16.h>

// 2D-MDLSTM (4 directions) + FC head for MI355X — round 18.
//
// R17 post-mortem: per-tile producer-consumer fusion appended a ~56 us tail
// (counter check: MfmaUtil 14.9 == 25*83/138.6, VALUBusy 32.3 == 53*83/138.6
// -> recurrence unchanged; tail VALU ~1% -> consumers SPINNING, not
// computing). Co-residency of 256 WGs is not schedulable-guaranteed; some
// producers started/finished ~55 us late and stalled their consumers.
// Fusion now triple-falsified (R14 grid-sync, R17 flags, R5/R10). Two-kernel
// structure restored; mdlstm below is R12 VERBATIM (measured 82.9 us).
//
// R18 lever: the fc kernel was latency-bound — 512-deep serial dependent
// global-load chain per thread (2 cols x 256 f) at 2 waves/CU (128 WGs x
// 4 waves): ~64 latency batches x ~200 cyc L2 ~= 6-10 us. Rewrite: 1024
// threads/WG, 1 col/thread with K split in half (128 loads/thread, 4x
// shorter chain), 16 waves/WG -> 8 waves/CU (4x TLP). Partial sums combine
// via LDS. mdlstm untouched -> any total delta attributes to fc alone.

#define GRIDN 28
#define BATCH 128
#define HID   64
#define NDIR  4
#define FC_HD 512
#define OUT_N 10
#define BT    2
#define NTHR  512
#define NSLOT 29          // 28 frontier rows + permanent-zero row (r = -1)
#define S_H   104         // f16/slot: [0,64) h | [64]=x [65]=1 [66,96)=0 | 8 pad
#define S_C   68          // float/slot: 64 c + 4 pad

typedef _Float16 f16;
typedef _Float16 f16x8 __attribute__((ext_vector_type(8)));
typedef float    f32x4 __attribute__((ext_vector_type(4)));

#define LOG2E  1.44269504088896340736f
#define LOG2E2 2.88539008177792681472f

__device__ __forceinline__ float rcpf(float x) { return __builtin_amdgcn_rcpf(x); }
__device__ __forceinline__ float ex2(float x)  { return __builtin_amdgcn_exp2f(x); }

__global__ __launch_bounds__(NTHR)
void mdlstm_kernel(const float* __restrict__ x,    // [B][28][28]
                   const float* __restrict__ Wx,   // [4][320]
                   const float* __restrict__ U,    // [4][128][320]
                   const float* __restrict__ bias, // [4][320]
                   float* __restrict__ Hout)       // [4][B][64]
{
    const int d    = blockIdx.x & 3;
    const int tile = blockIdx.x >> 2;     // 0..63 batch-pair
    const int tid  = threadIdx.x;
    const int lane = tid & 63;
    const int wave = tid >> 6;            // 0..7
    const int wm   = wave >> 2;           // tile parity 0/1
    const int wh   = wave & 3;            // h-subtile (n = wh*16 + l16)
    const int l16  = lane & 15;
    const int q    = lane >> 4;
    const int nb   = wh * 16 + l16;       // this lane's h index 0..63

    __shared__ __align__(16) f16 Fh[2][BT][NSLOT * S_H];
    __shared__ float             Fc[2][BT][NSLOT * S_C];
    __shared__ float             xs[GRIDN][GRIDN][BT];

    for (int i = tid; i < 2 * BT * NSLOT * S_H; i += NTHR) ((f16*)Fh)[i] = (f16)0.0f;
    for (int i = tid; i < 2 * BT * NSLOT * S_C; i += NTHR) ((float*)Fc)[i] = 0.0f;
    for (int i = tid; i < GRIDN * GRIDN * BT; i += NTHR) {
        int bl = i & 1, rc = i >> 1, c = rc % GRIDN, r = rc / GRIDN;
        int rr = (d & 2) ? (GRIDN - 1 - r) : r;
        int cc = (d & 1) ? (GRIDN - 1 - c) : c;
        xs[r][c][bl] = x[((tile * BT + bl) * GRIDN + rr) * GRIDN + cc];
    }

    // ---- B-fragments in registers, gate-scaled: 25 x f16x8 (100 regs)
    // sigmoid gates scaled by -log2e (sig = rcp(1+2^acc)); g gate by +2log2e.
    f16x8 bf[5][5];
#pragma unroll
    for (int g = 0; g < 5; ++g) {
        const float sc = (g == 4) ? LOG2E2 : -LOG2E;
        int n = g * 64 + nb;
#pragma unroll
        for (int ks = 0; ks < 4; ++ks) {
            f16x8 v;
            int kb = ks * 32 + q * 8;
#pragma unroll
            for (int j = 0; j < 8; ++j)
                v[j] = (f16)(sc * U[(d * 128 + kb + j) * 320 + n]);
            bf[g][ks] = v;
        }
        f16x8 v5 = {(f16)0, (f16)0, (f16)0, (f16)0, (f16)0, (f16)0, (f16)0, (f16)0};
        if (q == 0) {
            v5[0] = (f16)(sc * Wx[d * 320 + n]);
            v5[1] = (f16)(sc * bias[d * 320 + n]);
        }
        bf[g][4] = v5;
    }
    __syncthreads();   // zero-init complete

    // ones in the x-region ([65]=1) of every slot, both buffers; seed x(0,0)
    if (tid < 2 * BT * NSLOT) {
        int buf = tid / (BT * NSLOT), rem = tid % (BT * NSLOT);
        int b = rem / NSLOT, sl = rem % NSLOT;
        Fh[buf][b][sl * S_H + 65] = (f16)1.0f;
    }
    if (tid < BT) Fh[0][tid][27 * S_H + 64] = (f16)xs[0][0][tid];
    __syncthreads();

    // one anti-diagonal; br is a literal at every callsite -> const-folds
    auto step = [&](int t, int br) __attribute__((always_inline)) {
        const int bw  = br ^ 1;
        const int rlo = (t > GRIDN - 1) ? (t - (GRIDN - 1)) : 0;
        const int rhi = (t < GRIDN - 1) ? t : (GRIDN - 1);
        const int k   = rhi - rlo + 1;
        const int nM  = (2 * k + 15) >> 4;

        // stage x for diagonal t+1 into the write buffer (tail lanes of last wave)
        if (t < 2 * GRIDN - 2 && tid >= NTHR - 56) {
            int idx = tid - (NTHR - 56), b = idx & 1, j = idx >> 1;
            int rlo2 = (t + 1 > GRIDN - 1) ? (t + 1 - (GRIDN - 1)) : 0;
            int rhi2 = (t + 1 < GRIDN - 1) ? (t + 1) : (GRIDN - 1);
            if (j <= rhi2 - rlo2) {
                int r = rlo2 + j;
                Fh[bw][b][(27 - r) * S_H + 64] = (f16)xs[r][t + 1 - r][b];
            }
        }

        for (int mt = wm; mt < nM; mt += 2) {
            // ---- A fragments: task row mA -> (batch bA, grid row rA)
            int mA = mt * 16 + l16;
            int jA = mA >> 1; if (jA > k - 1) jA = k - 1;
            int bA = mA & 1;
            int slA = 27 - (rlo + jA);
            const f16* ab = &Fh[br][bA][slA * S_H];
            f16x8 a0 = *(const f16x8*)(ab + q * 8);              // h_left k 0..63
            f16x8 a1 = *(const f16x8*)(ab + 32 + q * 8);
            f16x8 a2 = *(const f16x8*)(ab + S_H + q * 8);        // h_up   k 64..127
            f16x8 a3 = *(const f16x8*)(ab + S_H + 32 + q * 8);
            f16x8 a4 = *(const f16x8*)(ab + 64 + q * 8);         // {x,1,0..} k 128..159

            // ---- epilogue addresses + c-state PRELOAD (before MFMAs: their
            // ~120 cyc LDS latency drains under the MFMA block)
            int j0  = mt * 8 + q * 2;
            int jj0 = (j0     > k - 1) ? k - 1 : j0;
            int jj1 = (j0 + 1 > k - 1) ? k - 1 : j0 + 1;
            int sl0 = 27 - (rlo + jj0);
            int sl1 = 27 - (rlo + jj1);
            const float* rp[4] = { &Fc[br][0][sl0 * S_C + nb], &Fc[br][1][sl0 * S_C + nb],
                                   &Fc[br][0][sl1 * S_C + nb], &Fc[br][1][sl1 * S_C + nb] };
            float pcl[4], pcu[4];
#pragma unroll
            for (int i = 0; i < 4; ++i) { pcl[i] = rp[i][0]; pcu[i] = rp[i][S_C]; }

            const f32x4 z4 = {0.f, 0.f, 0.f, 0.f};               // shared zero-C
            f32x4 acc[5];
#pragma unroll
            for (int g = 0; g < 5; ++g) acc[g] = __builtin_amdgcn_mfma_f32_16x16x32_f16(a4, bf[g][4], z4, 0, 0, 0);
#pragma unroll
            for (int g = 0; g < 5; ++g) acc[g] = __builtin_amdgcn_mfma_f32_16x16x32_f16(a0, bf[g][0], acc[g], 0, 0, 0);
#pragma unroll
            for (int g = 0; g < 5; ++g) acc[g] = __builtin_amdgcn_mfma_f32_16x16x32_f16(a1, bf[g][1], acc[g], 0, 0, 0);
#pragma unroll
            for (int g = 0; g < 5; ++g) acc[g] = __builtin_amdgcn_mfma_f32_16x16x32_f16(a2, bf[g][2], acc[g], 0, 0, 0);
#pragma unroll
            for (int g = 0; g < 5; ++g) acc[g] = __builtin_amdgcn_mfma_f32_16x16x32_f16(a3, bf[g][3], acc[g], 0, 0, 0);

            // ---- gates + state, BRANCHLESS, trans-merged.
            // acc0=-log2e*i  acc1=-log2e*f1  acc2=-log2e*f2  acc3=-log2e*o
            // acc4=+2log2e*g
            //   sig(i)*tanh(g)        = (tb-2)*rcp(ta*tb)
            //   sig(f1)*cl+sig(f2)*cu = (cl*tq+cu*tp)*rcp(tp*tq)
            //   sig(o)*tanh(cn)       = (te-2)*rcp(td*te), cn clamped to 22
            //     for te only (tanh(22)==1.0f exactly; prevents te=inf ->
            //     inf*0=NaN when the accumulated c exceeds 44 — the R11 bug).
            const int DC = (bw - br) * (BT * NSLOT * S_C);   // compile-time
            int ih0 = sl0 * S_H + nb, ih1 = sl1 * S_H + nb;
            f16* wh0 = &Fh[bw][0][0];
            f16* wh1 = &Fh[bw][1][0];
#pragma unroll
            for (int i = 0; i < 4; ++i) {
                float ta = 1.0f + ex2(acc[0][i]);
                float tp = 1.0f + ex2(acc[1][i]);
                float tq = 1.0f + ex2(acc[2][i]);
                float td = 1.0f + ex2(acc[3][i]);
                float tb = 1.0f + ex2(acc[4][i]);
                float cn = (tb - 2.0f) * rcpf(ta * tb)
                         + (pcl[i] * tq + pcu[i] * tp) * rcpf(tp * tq);
                float cnc = fminf(cn, 22.0f);
                float te = 1.0f + ex2(LOG2E2 * cnc);
                float hn = (te - 2.0f) * rcpf(td * te);
                *(float*)(rp[i] + DC) = cn;
                ((i & 1) ? wh1 : wh0)[(i < 2) ? ih0 : ih1] = (f16)hn;
            }
        }
        __syncthreads();
    };

    for (int tb = 0; tb < 27; ++tb) { step(2 * tb, 0); step(2 * tb + 1, 1); }
    step(54, 0);

    // final h(27,27): t=54 wrote buf 1, slot 0
    if (tid < BT * HID) {
        int bl = tid >> 6, h = tid & 63;
        Hout[(d * BATCH + tile * BT + bl) * HID + h] = (float)Fh[1][bl][h];
    }
}

// FC head, round 18: one WG of 1024 threads per batch row (16 waves/WG,
// 128 WGs -> 8 waves/CU on 128 CUs). z1: 1 col/thread with K split in
// half -> 128-deep load chain (was 512) and 4x the wave-level latency
// hiding; halves combine via LDS. z2/softmax unchanged in shape.
__global__ __launch_bounds__(1024)
void fc_kernel(const float* __restrict__ Hin,  // [4][B][64]
               const float* __restrict__ W1, const float* __restrict__ b1,
               const float* __restrict__ W2, const float* __restrict__ b2,
               float* __restrict__ out)        // [B][10]
{
    const int b   = blockIdx.x;
    const int tid = threadIdx.x;
    __shared__ float hrow[NDIR * HID];
    __shared__ float psum[2][FC_HD];
    __shared__ float z1[FC_HD];
    __shared__ float ps[32][16];
    __shared__ float z2[16];

    if (tid < NDIR * HID)
        hrow[tid] = Hin[(tid >> 6) * (BATCH * HID) + b * HID + (tid & 63)];
    __syncthreads();

    // ---- z1 partials: col = tid&511, K-half = tid>>9 (f in [h*128, h*128+128))
    {
        int col = tid & (FC_HD - 1);
        int hf  = tid >> 9;
        int f0  = hf * 128;
        float s = 0.0f;
#pragma unroll 16
        for (int f = 0; f < 128; ++f)
            s += hrow[f0 + f] * W1[(f0 + f) * FC_HD + col];
        psum[hf][col] = s;
    }
    __syncthreads();

    if (tid < FC_HD)
        z1[tid] = fmaxf(psum[0][tid] + psum[1][tid] + b1[tid], 0.0f);
    __syncthreads();

    // ---- z2 partials: j = tid&15 (10 used), slice = tid>>4 covers 16 k each
    if (tid < 512) {
        int j = tid & 15, sl = tid >> 4;
        float s = 0.0f;
        if (j < OUT_N) {
#pragma unroll
            for (int i = 0; i < 16; ++i) {
                int kk = sl * 16 + i;
                s += z1[kk] * W2[kk * OUT_N + j];
            }
        }
        ps[sl][j] = s;
    }
    __syncthreads();

    if (tid < OUT_N) {
        float s = b2[tid];
#pragma unroll
        for (int sl = 0; sl < 32; ++sl) s += ps[sl][tid];
        z2[tid] = s;
    }
    __syncthreads();

    if (tid == 0) {
        float m = z2[0];
        for (int j = 1; j < OUT_N; ++j) m = fmaxf(m, z2[j]);
        float sum = 0.0f, e[OUT_N];
        for (int j = 0; j < OUT_N; ++j) { e[j] = __expf(z2[j] - m); sum += e[j]; }
        float inv = 1.0f / sum;
        for (int j = 0; j < OUT_N; ++j) out[b * OUT_N + j] = e[j] * inv;
    }
}

extern "C" void kernel_launch(void* const* d_in, const int* in_sizes, int n_in,
                              void* d_out, int out_size, void* d_ws, size_t ws_size,
                              hipStream_t stream) {
    const float* x  = (const float*)d_in[0];
    const float* Wx = (const float*)d_in[1];
    const float* U  = (const float*)d_in[2];
    const float* bs = (const float*)d_in[3];
    const float* W1 = (const float*)d_in[4];
    const float* b1 = (const float*)d_in[5];
    const float* W2 = (const float*)d_in[6];
    const float* b2 = (const float*)d_in[7];
    float* out = (float*)d_out;
    float* Hws = (float*)d_ws;   // [4][128][64] fp32 = 128 KiB

    mdlstm_kernel<<<NDIR * (BATCH / BT), NTHR, 0, stream>>>(x, Wx, U, bs, Hws);
    fc_kernel<<<BATCH, 1024, 0, stream>>>(Hws, W1, b1, W2, b2, out);
}